// Round 8
// baseline (263.446 us; speedup 1.0000x reference)
//
#include <hip/hip_runtime.h>
#include <hip/hip_bf16.h>
#include <math.h>

using short8 = __attribute__((ext_vector_type(8))) short;
using f32x4  = __attribute__((ext_vector_type(4))) float;
using fv4    = __attribute__((ext_vector_type(4))) float;

#define EMB 768
#define CD  64
#define NSCEN 19
#define NCHUNKS (25 * 4)   // W1T: (24 emb + 1 bag) k-steps x 4 col-tiles, 512 bf16 each
#define BM 32              // rows per block
#define ROWP 776           // ushorts per LDS A-row (768 + 8): 1552 B = 97*16, even bank spread

__device__ __forceinline__ ushort f2bf(float x) {
    unsigned u = __float_as_uint(x);
    u += 0x7FFFu + ((u >> 16) & 1u);   // RNE
    return (ushort)(u >> 16);
}

__device__ __forceinline__ uint cvt2(float x, float y) {   // v_cvt_pk_bf16_f32
    __hip_bfloat162 h = __float22bfloat162_rn(make_float2(x, y));
    union { __hip_bfloat162 h; uint u; } c;
    c.h = h;
    return c.u;
}

__device__ __forceinline__ float4 ntl4(const float* p) {
    fv4 v = __builtin_nontemporal_load((const fv4*)p);
    return make_float4(v[0], v[1], v[2], v[3]);
}

// Pre-fragment B = [W1(768x64) ; P(32x64)] into bf16 wave-chunks of 512 elems:
// chunk c = ks*4+ct; element r = lane*8+j  <->  B[k = ks*32+(lane>>4)*8+j][col = ct*16+(lane&15)]
__global__ void prep_W1T(const float* __restrict__ table,
                         const float* __restrict__ W1,
                         ushort* __restrict__ W1T) {
    int e = blockIdx.x * 256 + threadIdx.x;      // 0 .. 51200
    if (e >= NCHUNKS * 512) return;
    int chunk = e >> 9, r = e & 511;
    int lane = r >> 3, j = r & 7;
    int ks = chunk >> 2, ct = chunk & 3;
    int col = ct * 16 + (lane & 15);
    int k = ks * 32 + ((lane >> 4) << 3) + j;
    float v = 0.f;
    if (k < EMB) {
        v = W1[(size_t)k * CD + col];
    } else {
        int s = k - EMB;
        if (s < NSCEN) {
            for (int d = 0; d < 16; ++d)
                v += table[s * 16 + d] * W1[(size_t)(EMB + s * 16 + d) * CD + col];
        }
    }
    W1T[e] = f2bf(v);
}

__global__ __launch_bounds__(512, 4)
void scorer_mfma(const float* __restrict__ emb,
                 const int* __restrict__ ids,
                 const float* __restrict__ mask,
                 const ushort* __restrict__ W1T,
                 const float* __restrict__ b1,
                 const float* __restrict__ W2,
                 const float* __restrict__ b2,
                 float* __restrict__ out) {
    __shared__ ushort Abuf[BM][ROWP];   // 49.7 KB staged A (bf16)
    __shared__ float  bagf[BM][21];     // f32 histogram, [..,20]=cnt
    __shared__ ushort bagb[BM][40];     // bf16 hist/cnt (cols 0..31 used; stride 40 = even banks)
    __shared__ float  part[2][16][4];   // cross-wave W2-dot partials

    const int t    = threadIdx.x;
    const int w    = t >> 6;       // wave 0..7
    const int lane = t & 63;
    const int lr   = lane & 15;
    const int lg   = lane >> 4;
    const int rg   = w & 1;        // wave's row-group (16 rows)
    const int ct   = w >> 1;       // wave's col-tile (16 cols)
    const int row0 = blockIdx.x * BM;

    // ================= one all-at-top load burst (max MLP + page locality) ========
    // A: thread t owns 192 contiguous bytes of the block's 96 KB region,
    //    row = t>>4, float-col = (t&15)*48  (3072/192 = 16 threads per row)
    float4 sv[12];
    {
        const float* src = emb + (size_t)row0 * EMB + (size_t)t * 48;
#pragma unroll
        for (int i = 0; i < 12; ++i) sv[i] = ntl4(src + i * 4);
    }
    int4 iv; float4 mv;
    if (t < 256) {   // bag inputs: 8 threads/row, 4 slots each
        const int r = t >> 3, p = t & 7;
        iv = ((const int4*)(ids + (size_t)(row0 + r) * 32))[p];
        mv = ((const float4*)(mask + (size_t)(row0 + r) * 32))[p];
    }
    const int   ccol = ct * 16 + lr;
    const float b1v  = b1[ccol];
    const float w2v  = W2[ccol];
    const float b2v  = b2[0];

    for (int e = t; e < BM * 21; e += 512) ((float*)bagf)[e] = 0.f;
    __syncthreads();

    // ---- bag histogram (LDS atomics; mask is exact 0/1 so sums are order-exact)
    if (t < 256) {
        const int r = t >> 3;
        atomicAdd(&bagf[r][iv.x], mv.x);
        atomicAdd(&bagf[r][iv.y], mv.y);
        atomicAdd(&bagf[r][iv.z], mv.z);
        atomicAdd(&bagf[r][iv.w], mv.w);
        atomicAdd(&bagf[r][20], mv.x + mv.y + mv.z + mv.w);
    }
    __syncthreads();
    if (t < BM) {
        float rc = 1.0f / fmaxf(bagf[t][20], 1.0f);
        uint u[16];
#pragma unroll
        for (int p = 0; p < 16; ++p) {
            float x0 = (2 * p     < NSCEN) ? bagf[t][2 * p] * rc     : 0.f;
            float x1 = (2 * p + 1 < NSCEN) ? bagf[t][2 * p + 1] * rc : 0.f;
            u[p] = cvt2(x0, x1);
        }
#pragma unroll
        for (int q = 0; q < 4; ++q)
            *(uint4*)&bagb[t][q * 8] = make_uint4(u[4 * q], u[4 * q + 1], u[4 * q + 2], u[4 * q + 3]);
    }

    // ---- convert + store staged A (f32 -> bf16), then the single pre-compute barrier
    {
        ushort* dst = &Abuf[t >> 4][(t & 15) * 48];
#pragma unroll
        for (int g = 0; g < 3; ++g) {
            uint u0 = cvt2(sv[4 * g].x,     sv[4 * g].y);
            uint u1 = cvt2(sv[4 * g].z,     sv[4 * g].w);
            uint u2 = cvt2(sv[4 * g + 1].x, sv[4 * g + 1].y);
            uint u3 = cvt2(sv[4 * g + 1].z, sv[4 * g + 1].w);
            uint u4 = cvt2(sv[4 * g + 2].x, sv[4 * g + 2].y);
            uint u5 = cvt2(sv[4 * g + 2].z, sv[4 * g + 2].w);
            uint u6 = cvt2(sv[4 * g + 3].x, sv[4 * g + 3].y);
            uint u7 = cvt2(sv[4 * g + 3].z, sv[4 * g + 3].w);
            *(uint4*)(dst + g * 16)     = make_uint4(u0, u1, u2, u3);
            *(uint4*)(dst + g * 16 + 8) = make_uint4(u4, u5, u6, u7);
        }
    }
    __syncthreads();

    // ================= compute: 24 emb k-steps + 1 bag k-step, no barriers ========
    const ushort* wp = W1T + lane * 8;
    f32x4 acc = (f32x4)0.f;
    short8 bb[4];

#define LOADB(slot, kk) bb[slot] = *(const short8*)(wp + (((kk) * 4 + ct) << 9))

    LOADB(0, 0); LOADB(1, 1); LOADB(2, 2); LOADB(3, 3);
#pragma unroll
    for (int ks = 0; ks < 24; ++ks) {
        short8 a = *(const short8*)&Abuf[rg * 16 + lr][ks * 32 + lg * 8];
        acc = __builtin_amdgcn_mfma_f32_16x16x32_bf16(a, bb[ks & 3], acc, 0, 0, 0);
        if (ks + 4 <= 24) LOADB(ks & 3, ks + 4);
    }
    {
        short8 a = *(const short8*)&bagb[rg * 16 + lr][lg * 8];
        acc = __builtin_amdgcn_mfma_f32_16x16x32_bf16(a, bb[0], acc, 0, 0, 0);
    }
#undef LOADB

    // ================= epilogue: relu + W2-dot, cross-wave reduce, tanh ===========
    float p0 = 0.f, p1 = 0.f, p2 = 0.f, p3 = 0.f;
    p0 = fmaxf(acc[0] + b1v, 0.f) * w2v;
    p1 = fmaxf(acc[1] + b1v, 0.f) * w2v;
    p2 = fmaxf(acc[2] + b1v, 0.f) * w2v;
    p3 = fmaxf(acc[3] + b1v, 0.f) * w2v;
#pragma unroll
    for (int d = 1; d < 16; d <<= 1) {
        p0 += __shfl_xor(p0, d);
        p1 += __shfl_xor(p1, d);
        p2 += __shfl_xor(p2, d);
        p3 += __shfl_xor(p3, d);
    }
    if (lr == 0) {
        part[rg][lg * 4 + 0][ct] = p0;
        part[rg][lg * 4 + 1][ct] = p1;
        part[rg][lg * 4 + 2][ct] = p2;
        part[rg][lg * 4 + 3][ct] = p3;
    }
    __syncthreads();
    if (t < BM) {
        float s = part[t >> 4][t & 15][0] + part[t >> 4][t & 15][1]
                + part[t >> 4][t & 15][2] + part[t >> 4][t & 15][3];
        out[row0 + t] = tanhf(s + b2v);
    }
}

extern "C" void kernel_launch(void* const* d_in, const int* in_sizes, int n_in,
                              void* d_out, int out_size, void* d_ws, size_t ws_size,
                              hipStream_t stream) {
    const float* emb   = (const float*)d_in[0];
    const int*   ids   = (const int*)d_in[1];
    const float* mask  = (const float*)d_in[2];
    const float* table = (const float*)d_in[3];
    const float* W1    = (const float*)d_in[4];
    const float* b1    = (const float*)d_in[5];
    const float* W2    = (const float*)d_in[6];
    const float* b2    = (const float*)d_in[7];
    float* out  = (float*)d_out;
    ushort* W1T = (ushort*)d_ws;   // 51200 bf16 = 100 KB

    prep_W1T<<<200, 256, 0, stream>>>(table, W1, W1T);
    const int nblocks = out_size / BM;   // 4096
    scorer_mfma<<<nblocks, 512, 0, stream>>>(emb, ids, mask, W1T, b1, W2, b2, out);
}

// Round 9
// 113.533 us; speedup vs baseline: 2.3204x; 2.3204x over previous
//
#include <hip/hip_runtime.h>
#include <hip/hip_bf16.h>
#include <math.h>

using short8 = __attribute__((ext_vector_type(8))) short;
using f32x4  = __attribute__((ext_vector_type(4))) float;
using fv4    = __attribute__((ext_vector_type(4))) float;

#define EMB 768
#define CD  64
#define NSCEN 19
#define KSTEPS 24            // 768 / 32
#define NCHUNKS (25 * 4)     // (24 emb + 1 bag) k-steps x 4 col-tiles, 512 bf16 each

__device__ __forceinline__ ushort f2bf(float x) {
    unsigned u = __float_as_uint(x);
    u += 0x7FFFu + ((u >> 16) & 1u);   // round-to-nearest-even
    return (ushort)(u >> 16);
}

// packed f32x2 -> bf16x2 via v_cvt_pk_bf16_f32 (compiler emits from the API)
__device__ __forceinline__ uint cvt2(float x, float y) {
    __hip_bfloat162 h = __float22bfloat162_rn(make_float2(x, y));
    union { __hip_bfloat162 h; uint u; } c;
    c.h = h;
    return c.u;
}

// Pre-fragment B = [W1(768x64) ; P(32x64)] into bf16 wave-chunks of 512 elems:
// chunk c = ks*4+ct; element r = lane*8+j  <->  B[k = ks*32+(lane>>4)*8+j][col = ct*16+(lane&15)]
// P[s][col] = sum_d table[s][d] * W1[768+s*16+d][col]  (s<19), else 0.
__global__ void prep_W1T(const float* __restrict__ table,
                         const float* __restrict__ W1,
                         ushort* __restrict__ W1T) {
    int e = blockIdx.x * 256 + threadIdx.x;      // 0 .. 51200
    if (e >= NCHUNKS * 512) return;
    int chunk = e >> 9, r = e & 511;
    int lane = r >> 3, j = r & 7;
    int ks = chunk >> 2, ct = chunk & 3;
    int col = ct * 16 + (lane & 15);
    int k = ks * 32 + ((lane >> 4) << 3) + j;
    float v = 0.f;
    if (k < EMB) {
        v = W1[(size_t)k * CD + col];
    } else {
        int s = k - EMB;
        if (s < NSCEN) {
            for (int d = 0; d < 16; ++d)
                v += table[s * 16 + d] * W1[(size_t)(EMB + s * 16 + d) * CD + col];
        }
    }
    W1T[e] = f2bf(v);
}

__global__ __launch_bounds__(512, 4)
void scorer_mfma(const float* __restrict__ emb,
                 const int* __restrict__ ids,
                 const float* __restrict__ mask,
                 const ushort* __restrict__ W1T,
                 const float* __restrict__ b1,
                 const float* __restrict__ W2,
                 const float* __restrict__ b2,
                 float* __restrict__ out) {
    __shared__ float  bagf[256][21];   // f32 histogram, stride 21 breaks bank aliasing
    __shared__ ushort bagb[256][32];   // bf16 hist/cnt, zero-padded to K=32

    const int t    = threadIdx.x;
    const int w    = t >> 6;       // wave 0..7, owns rows w*32..w*32+31
    const int lane = t & 63;
    const int lr   = lane & 15;    // A-row / B-col residue
    const int lg   = lane >> 4;    // k-group (8 wide) / C row-group
    const int row0 = blockIdx.x * 256;

    // ---- bag histogram: thread t owns row t (t<256)
    if (t < 256) {
#pragma unroll
        for (int s = 0; s < NSCEN; ++s) bagf[t][s] = 0.f;
        const int*   idrow = ids  + (size_t)(row0 + t) * 32;
        const float* mrow  = mask + (size_t)(row0 + t) * 32;
        float cnt = 0.f;
#pragma unroll 2
        for (int q = 0; q < 8; ++q) {
            int4   i4 = ((const int4*)idrow)[q];
            float4 m4 = ((const float4*)mrow)[q];
            bagf[t][i4.x] += m4.x; cnt += m4.x;
            bagf[t][i4.y] += m4.y; cnt += m4.y;
            bagf[t][i4.z] += m4.z; cnt += m4.z;
            bagf[t][i4.w] += m4.w; cnt += m4.w;
        }
        float rc = 1.0f / fmaxf(cnt, 1.0f);
#pragma unroll
        for (int s = 0; s < 32; ++s)
            bagb[t][s] = (s < NSCEN) ? f2bf(bagf[t][s] * rc) : (ushort)0;
    }
    __syncthreads();   // the only block barrier

    // ---- barrier-free MFMA stream: 32 rows x 64 cols per wave
    const float*  ap = emb + (size_t)(row0 + w * 32 + lr) * EMB + (lg << 3);
    const ushort* wp = W1T + (lane << 3);

    f32x4 acc[2][4];
#pragma unroll
    for (int i = 0; i < 2; ++i)
#pragma unroll
        for (int j = 0; j < 4; ++j) acc[i][j] = (f32x4)0.f;

    fv4    aA[2][2], aB[2][2];
    short8 bbA[4], bbB[4];

// nontemporal A-loads: emb is read-once (402 MB) — don't let it thrash L2/L3
#define LOADA(dst, kks) do {                                             \
    const float* _p = ap + (kks) * 32;                                   \
    dst[0][0] = __builtin_nontemporal_load((const fv4*)(_p));            \
    dst[0][1] = __builtin_nontemporal_load((const fv4*)(_p + 4));        \
    dst[1][0] = __builtin_nontemporal_load((const fv4*)(_p + 16 * EMB)); \
    dst[1][1] = __builtin_nontemporal_load((const fv4*)(_p + 16 * EMB + 4)); \
} while (0)

#define LOADB(dst, kks) do {                                   \
    const ushort* _q = wp + ((size_t)(kks) << 11);             \
    dst[0] = *(const short8*)(_q);                             \
    dst[1] = *(const short8*)(_q + 512);                       \
    dst[2] = *(const short8*)(_q + 1024);                      \
    dst[3] = *(const short8*)(_q + 1536);                      \
} while (0)

#define STEP(areg, breg) do {                                              \
    short8 _fa[2];                                                         \
    _Pragma("unroll")                                                      \
    for (int _rt = 0; _rt < 2; ++_rt) {                                    \
        union { uint u[4]; short8 s; } _c;                                 \
        _c.u[0] = cvt2(areg[_rt][0][0], areg[_rt][0][1]);                  \
        _c.u[1] = cvt2(areg[_rt][0][2], areg[_rt][0][3]);                  \
        _c.u[2] = cvt2(areg[_rt][1][0], areg[_rt][1][1]);                  \
        _c.u[3] = cvt2(areg[_rt][1][2], areg[_rt][1][3]);                  \
        _fa[_rt] = _c.s;                                                   \
    }                                                                      \
    _Pragma("unroll")                                                      \
    for (int _rt = 0; _rt < 2; ++_rt) {                                    \
        acc[_rt][0] = __builtin_amdgcn_mfma_f32_16x16x32_bf16(_fa[_rt], breg[0], acc[_rt][0], 0, 0, 0); \
        acc[_rt][1] = __builtin_amdgcn_mfma_f32_16x16x32_bf16(_fa[_rt], breg[1], acc[_rt][1], 0, 0, 0); \
        acc[_rt][2] = __builtin_amdgcn_mfma_f32_16x16x32_bf16(_fa[_rt], breg[2], acc[_rt][2], 0, 0, 0); \
        acc[_rt][3] = __builtin_amdgcn_mfma_f32_16x16x32_bf16(_fa[_rt], breg[3], acc[_rt][3], 0, 0, 0); \
    }                                                                      \
} while (0)

    LOADA(aA, 0);
    LOADB(bbA, 0);
#pragma unroll 1
    for (int ks = 0; ks < KSTEPS; ks += 2) {
        LOADA(aB, ks + 1);
        LOADB(bbB, ks + 1);
        STEP(aA, bbA);
        if (ks + 2 < KSTEPS) {
            LOADA(aA, ks + 2);
            LOADB(bbA, ks + 2);
        } else {
            LOADB(bbA, KSTEPS);          // prefetch bag-B chunk
        }
        STEP(aB, bbB);
    }

    // ---- bag k-step (ks = 24): A from LDS (bf16 direct), B = bbA (prefetched)
    {
        short8 ab[2];
        ab[0] = *(const short8*)&bagb[w * 32 + lr][lg << 3];
        ab[1] = *(const short8*)&bagb[w * 32 + 16 + lr][lg << 3];
#pragma unroll
        for (int rt = 0; rt < 2; ++rt) {
            acc[rt][0] = __builtin_amdgcn_mfma_f32_16x16x32_bf16(ab[rt], bbA[0], acc[rt][0], 0, 0, 0);
            acc[rt][1] = __builtin_amdgcn_mfma_f32_16x16x32_bf16(ab[rt], bbA[1], acc[rt][1], 0, 0, 0);
            acc[rt][2] = __builtin_amdgcn_mfma_f32_16x16x32_bf16(ab[rt], bbA[2], acc[rt][2], 0, 0, 0);
            acc[rt][3] = __builtin_amdgcn_mfma_f32_16x16x32_bf16(ab[rt], bbA[3], acc[rt][3], 0, 0, 0);
        }
    }

    // ---- epilogue: bias + relu + dot(W2) + tanh
    float b1v[4], w2v[4];
#pragma unroll
    for (int ct = 0; ct < 4; ++ct) {
        int c = ct * 16 + lr;
        b1v[ct] = b1[c];
        w2v[ct] = W2[c];
    }
    const float b2v = b2[0];
#pragma unroll
    for (int rt = 0; rt < 2; ++rt) {
#pragma unroll
        for (int r = 0; r < 4; ++r) {
            float p = 0.f;
#pragma unroll
            for (int ct = 0; ct < 4; ++ct) {
                float h = acc[rt][ct][r] + b1v[ct];
                p += fmaxf(h, 0.f) * w2v[ct];
            }
            p += __shfl_xor(p, 1);
            p += __shfl_xor(p, 2);
            p += __shfl_xor(p, 4);
            p += __shfl_xor(p, 8);
            if (lr == 0)
                out[row0 + w * 32 + rt * 16 + (lg << 2) + r] = tanhf(p + b2v);
        }
    }
#undef LOADA
#undef LOADB
#undef STEP
}

extern "C" void kernel_launch(void* const* d_in, const int* in_sizes, int n_in,
                              void* d_out, int out_size, void* d_ws, size_t ws_size,
                              hipStream_t stream) {
    const float* emb   = (const float*)d_in[0];
    const int*   ids   = (const int*)d_in[1];
    const float* mask  = (const float*)d_in[2];
    const float* table = (const float*)d_in[3];
    const float* W1    = (const float*)d_in[4];
    const float* b1    = (const float*)d_in[5];
    const float* W2    = (const float*)d_in[6];
    const float* b2    = (const float*)d_in[7];
    float* out  = (float*)d_out;
    ushort* W1T = (ushort*)d_ws;   // 51200 bf16 = 100 KB

    prep_W1T<<<200, 256, 0, stream>>>(table, W1, W1T);
    const int nblocks = out_size / 256;   // 512
    scorer_mfma<<<nblocks, 512, 0, stream>>>(emb, ids, mask, W1T, b1, W2, b2, out);
}

// Round 10
// 95.387 us; speedup vs baseline: 2.7619x; 1.1902x over previous
//
#include <hip/hip_runtime.h>
#include <hip/hip_bf16.h>
#include <math.h>

using short8 = __attribute__((ext_vector_type(8))) short;
using f32x4  = __attribute__((ext_vector_type(4))) float;
using fv4    = __attribute__((ext_vector_type(4))) float;

#define EMB 768
#define CD  64
#define NSCEN 19
#define KSTEPS 24            // 768 / 32
#define NCHUNKS (25 * 4)     // (24 emb + 1 bag) k-steps x 4 col-tiles, 512 bf16 each
#define QB 14336             // ushorts per LDS B quarter-buffer (28 KB)

__device__ __forceinline__ ushort f2bf(float x) {
    unsigned u = __float_as_uint(x);
    u += 0x7FFFu + ((u >> 16) & 1u);   // RNE
    return (ushort)(u >> 16);
}

// packed f32x2 -> bf16x2 (v_cvt_pk_bf16_f32)
__device__ __forceinline__ uint cvt2(float x, float y) {
    __hip_bfloat162 h = __float22bfloat162_rn(make_float2(x, y));
    union { __hip_bfloat162 h; uint u; } c;
    c.h = h;
    return c.u;
}

// Pre-fragment B = [W1(768x64) ; P(32x64)] into bf16 wave-chunks of 512 elems:
// chunk c = ks*4+ct; element r = lane*8+j  <->  B[k = ks*32+(lane>>4)*8+j][col = ct*16+(lane&15)]
__global__ void prep_W1T(const float* __restrict__ table,
                         const float* __restrict__ W1,
                         ushort* __restrict__ W1T) {
    int e = blockIdx.x * 256 + threadIdx.x;      // 0 .. 51200
    if (e >= NCHUNKS * 512) return;
    int chunk = e >> 9, r = e & 511;
    int lane = r >> 3, j = r & 7;
    int ks = chunk >> 2, ct = chunk & 3;
    int col = ct * 16 + (lane & 15);
    int k = ks * 32 + ((lane >> 4) << 3) + j;
    float v = 0.f;
    if (k < EMB) {
        v = W1[(size_t)k * CD + col];
    } else {
        int s = k - EMB;
        if (s < NSCEN) {
            for (int d = 0; d < 16; ++d)
                v += table[s * 16 + d] * W1[(size_t)(EMB + s * 16 + d) * CD + col];
        }
    }
    W1T[e] = f2bf(v);
}

__global__ __launch_bounds__(512, 4)
void scorer_mfma(const float* __restrict__ emb,
                 const int* __restrict__ ids,
                 const float* __restrict__ mask,
                 const ushort* __restrict__ W1T,
                 const float* __restrict__ b1,
                 const float* __restrict__ W2,
                 const float* __restrict__ b2,
                 float* __restrict__ out) {
    __shared__ __align__(16) ushort Bq[2][QB];    // 2 x 28 KB B quarter-buffers
    __shared__ __align__(16) ushort bagb[256][32];// bf16 hist/cnt, K=32 zero-padded
    // bagf overlays Bq[1] (dead before any Bq[1] B-data is written)
    float* bagf = (float*)&Bq[1][0];              // [256][21], 21504 B <= 28672

    const int t    = threadIdx.x;
    const int w    = t >> 6;       // wave 0..7, owns rows w*32..w*32+31
    const int lane = t & 63;
    const int lr   = lane & 15;
    const int lg   = lane >> 4;
    const int row0 = blockIdx.x * 256;

    // ---- quarter-fill machinery: reg-staged global->LDS, issued a quarter early
    uint4 f0, f1, f2, f3;
#define ISSUE_FILL(qs) do {                                                  \
    const uint* _g = (const uint*)((const char*)W1T + (size_t)(qs) * 4096);  \
    f0 = *(const uint4*)(_g + (t)        * 4);                               \
    f1 = *(const uint4*)(_g + (t + 512)  * 4);                               \
    f2 = *(const uint4*)(_g + (t + 1024) * 4);                               \
    if (t < 256) f3 = *(const uint4*)(_g + (t + 1536) * 4);                  \
} while (0)
#define WRITE_FILL(bufi) do {                                                \
    uint* _l = (uint*)&Bq[bufi][0];                                          \
    *(uint4*)(_l + (t)        * 4) = f0;                                     \
    *(uint4*)(_l + (t + 512)  * 4) = f1;                                     \
    *(uint4*)(_l + (t + 1024) * 4) = f2;                                     \
    if (t < 256) *(uint4*)(_l + (t + 1536) * 4) = f3;                        \
} while (0)

    ISSUE_FILL(0);   // quarter 0 (k-steps 0-5 + pad) in flight during histogram

    // ---- bag histogram: thread t owns row t (t<256), exclusive column
    if (t < 256) {
#pragma unroll
        for (int s = 0; s < NSCEN; ++s) bagf[t * 21 + s] = 0.f;
        const int*   idrow = ids  + (size_t)(row0 + t) * 32;
        const float* mrow  = mask + (size_t)(row0 + t) * 32;
        float cnt = 0.f;
#pragma unroll 2
        for (int q = 0; q < 8; ++q) {
            int4   i4 = ((const int4*)idrow)[q];
            float4 m4 = ((const float4*)mrow)[q];
            bagf[t * 21 + i4.x] += m4.x; cnt += m4.x;
            bagf[t * 21 + i4.y] += m4.y; cnt += m4.y;
            bagf[t * 21 + i4.z] += m4.z; cnt += m4.z;
            bagf[t * 21 + i4.w] += m4.w; cnt += m4.w;
        }
        float rc = 1.0f / fmaxf(cnt, 1.0f);
#pragma unroll
        for (int s = 0; s < 32; ++s)
            bagb[t][s] = (s < NSCEN) ? f2bf(bagf[t * 21 + s] * rc) : (ushort)0;
    }

    WRITE_FILL(0);     // Bq0 <- quarter 0
    ISSUE_FILL(6);     // quarter 1 (k-steps 6-11)
    __syncthreads();   // bagb + Bq0 ready; bagf dead

    // ---- MFMA stream: A direct from HBM (the ONLY steady-state vmem traffic),
    //      B from LDS quarter-buffers via conflict-free ds_read_b128
    const float* ap = emb + (size_t)(row0 + w * 32 + lr) * EMB + (lg << 3);

    f32x4 acc[2][4];
#pragma unroll
    for (int i = 0; i < 2; ++i)
#pragma unroll
        for (int j = 0; j < 4; ++j) acc[i][j] = (f32x4)0.f;

    fv4    aA[2][2], aB[2][2];
    short8 bqr[4];

#define LOADA(dst, kks) do {                                   \
    const float* _p = ap + (kks) * 32;                         \
    dst[0][0] = *(const fv4*)(_p);                             \
    dst[0][1] = *(const fv4*)(_p + 4);                         \
    dst[1][0] = *(const fv4*)(_p + 16 * EMB);                  \
    dst[1][1] = *(const fv4*)(_p + 16 * EMB + 4);              \
} while (0)

#define LDSB(bufi, ksl) do {                                   \
    const ushort* _l = &Bq[bufi][(ksl) * 2048 + lane * 8];     \
    bqr[0] = *(const short8*)(_l);                             \
    bqr[1] = *(const short8*)(_l + 512);                       \
    bqr[2] = *(const short8*)(_l + 1024);                      \
    bqr[3] = *(const short8*)(_l + 1536);                      \
} while (0)

#define STEP(areg) do {                                                     \
    short8 _fa[2];                                                          \
    _Pragma("unroll")                                                       \
    for (int _rt = 0; _rt < 2; ++_rt) {                                     \
        union { uint u[4]; short8 s; } _c;                                  \
        _c.u[0] = cvt2(areg[_rt][0][0], areg[_rt][0][1]);                   \
        _c.u[1] = cvt2(areg[_rt][0][2], areg[_rt][0][3]);                   \
        _c.u[2] = cvt2(areg[_rt][1][0], areg[_rt][1][1]);                   \
        _c.u[3] = cvt2(areg[_rt][1][2], areg[_rt][1][3]);                   \
        _fa[_rt] = _c.s;                                                    \
    }                                                                       \
    _Pragma("unroll")                                                       \
    for (int _rt = 0; _rt < 2; ++_rt) {                                     \
        acc[_rt][0] = __builtin_amdgcn_mfma_f32_16x16x32_bf16(_fa[_rt], bqr[0], acc[_rt][0], 0, 0, 0); \
        acc[_rt][1] = __builtin_amdgcn_mfma_f32_16x16x32_bf16(_fa[_rt], bqr[1], acc[_rt][1], 0, 0, 0); \
        acc[_rt][2] = __builtin_amdgcn_mfma_f32_16x16x32_bf16(_fa[_rt], bqr[2], acc[_rt][2], 0, 0, 0); \
        acc[_rt][3] = __builtin_amdgcn_mfma_f32_16x16x32_bf16(_fa[_rt], bqr[3], acc[_rt][3], 0, 0, 0); \
    }                                                                       \
} while (0)

// one quarter of 6 emb k-steps reading B from buffer bufi, global steps qs..qs+5
#define QUARTER(bufi, qs) do {                                              \
    _Pragma("unroll")                                                       \
    for (int _ksl = 0; _ksl < 6; ++_ksl) {                                  \
        const int _ks = (qs) + _ksl;                                        \
        LDSB(bufi, _ksl);                                                   \
        if ((_ks & 1) == 0) {                                               \
            if (_ks + 1 <= 23) LOADA(aB, _ks + 1);                          \
            STEP(aA);                                                       \
        } else {                                                            \
            if (_ks + 1 <= 23) LOADA(aA, _ks + 1);                          \
            STEP(aB);                                                       \
        }                                                                   \
    }                                                                       \
} while (0)

    LOADA(aA, 0);

    // Q0: compute from Bq0; fill Bq1 (q1 regs already in flight), issue q2
    WRITE_FILL(1);
    ISSUE_FILL(12);
    QUARTER(0, 0);
    __syncthreads();   // Bq1 ready; Bq0 free

    // Q1: compute from Bq1; fill Bq0 with q2, issue q3
    WRITE_FILL(0);
    ISSUE_FILL(18);
    QUARTER(1, 6);
    __syncthreads();   // Bq0 ready; Bq1 free

    // Q2: compute from Bq0; fill Bq1 with q3 (k-steps 18-24 incl. bag chunk)
    WRITE_FILL(1);
    QUARTER(0, 12);
    __syncthreads();   // Bq1 ready

    // Q3: compute from Bq1 (6 emb steps + bag step at local chunk 6)
    QUARTER(1, 18);
    {
        short8 ab[2];
        ab[0] = *(const short8*)&bagb[w * 32 + lr][lg << 3];
        ab[1] = *(const short8*)&bagb[w * 32 + 16 + lr][lg << 3];
        LDSB(1, 6);
#pragma unroll
        for (int rt = 0; rt < 2; ++rt) {
            acc[rt][0] = __builtin_amdgcn_mfma_f32_16x16x32_bf16(ab[rt], bqr[0], acc[rt][0], 0, 0, 0);
            acc[rt][1] = __builtin_amdgcn_mfma_f32_16x16x32_bf16(ab[rt], bqr[1], acc[rt][1], 0, 0, 0);
            acc[rt][2] = __builtin_amdgcn_mfma_f32_16x16x32_bf16(ab[rt], bqr[2], acc[rt][2], 0, 0, 0);
            acc[rt][3] = __builtin_amdgcn_mfma_f32_16x16x32_bf16(ab[rt], bqr[3], acc[rt][3], 0, 0, 0);
        }
    }

    // ---- epilogue: bias + relu + dot(W2) + tanh
    float b1v[4], w2v[4];
#pragma unroll
    for (int ct = 0; ct < 4; ++ct) {
        int c = ct * 16 + lr;
        b1v[ct] = b1[c];
        w2v[ct] = W2[c];
    }
    const float b2v = b2[0];
#pragma unroll
    for (int rt = 0; rt < 2; ++rt) {
#pragma unroll
        for (int r = 0; r < 4; ++r) {
            float p = 0.f;
#pragma unroll
            for (int ct = 0; ct < 4; ++ct) {
                float h = acc[rt][ct][r] + b1v[ct];
                p += fmaxf(h, 0.f) * w2v[ct];
            }
            p += __shfl_xor(p, 1);
            p += __shfl_xor(p, 2);
            p += __shfl_xor(p, 4);
            p += __shfl_xor(p, 8);
            if (lr == 0)
                out[row0 + w * 32 + rt * 16 + (lg << 2) + r] = tanhf(p + b2v);
        }
    }
#undef ISSUE_FILL
#undef WRITE_FILL
#undef LOADA
#undef LDSB
#undef STEP
#undef QUARTER
}

extern "C" void kernel_launch(void* const* d_in, const int* in_sizes, int n_in,
                              void* d_out, int out_size, void* d_ws, size_t ws_size,
                              hipStream_t stream) {
    const float* emb   = (const float*)d_in[0];
    const int*   ids   = (const int*)d_in[1];
    const float* mask  = (const float*)d_in[2];
    const float* table = (const float*)d_in[3];
    const float* W1    = (const float*)d_in[4];
    const float* b1    = (const float*)d_in[5];
    const float* W2    = (const float*)d_in[6];
    const float* b2    = (const float*)d_in[7];
    float* out  = (float*)d_out;
    ushort* W1T = (ushort*)d_ws;   // 51200 bf16 = 100 KB

    prep_W1T<<<200, 256, 0, stream>>>(table, W1, W1T);
    const int nblocks = out_size / 256;   // 512
    scorer_mfma<<<nblocks, 512, 0, stream>>>(emb, ids, mask, W1T, b1, W2, b2, out);
}

// Round 11
// 91.482 us; speedup vs baseline: 2.8798x; 1.0427x over previous
//
#include <hip/hip_runtime.h>
#include <hip/hip_bf16.h>
#include <math.h>

using short8 = __attribute__((ext_vector_type(8))) short;
using f32x4  = __attribute__((ext_vector_type(4))) float;
using fv4    = __attribute__((ext_vector_type(4))) float;

#define EMB 768
#define CD  64
#define NSCEN 19
#define KSTEPS 24            // 768 / 32
#define NCHUNKS (25 * 4)     // (24 emb + 1 bag) k-steps x 4 col-tiles, 512 bf16 each
#define QB 14336             // ushorts per LDS B quarter-buffer (28 KB)

__device__ __forceinline__ ushort f2bf(float x) {
    unsigned u = __float_as_uint(x);
    u += 0x7FFFu + ((u >> 16) & 1u);   // RNE
    return (ushort)(u >> 16);
}

// packed f32x2 -> bf16x2 (v_cvt_pk_bf16_f32)
__device__ __forceinline__ uint cvt2(float x, float y) {
    __hip_bfloat162 h = __float22bfloat162_rn(make_float2(x, y));
    union { __hip_bfloat162 h; uint u; } c;
    c.h = h;
    return c.u;
}

// Pre-fragment B = [W1(768x64) ; P(32x64)] into bf16 wave-chunks of 512 elems:
// chunk c = ks*4+ct; element r = lane*8+j  <->  B[k = ks*32+(lane>>4)*8+j][col = ct*16+(lane&15)]
__global__ void prep_W1T(const float* __restrict__ table,
                         const float* __restrict__ W1,
                         ushort* __restrict__ W1T) {
    int e = blockIdx.x * 256 + threadIdx.x;      // 0 .. 51200
    if (e >= NCHUNKS * 512) return;
    int chunk = e >> 9, r = e & 511;
    int lane = r >> 3, j = r & 7;
    int ks = chunk >> 2, ct = chunk & 3;
    int col = ct * 16 + (lane & 15);
    int k = ks * 32 + ((lane >> 4) << 3) + j;
    float v = 0.f;
    if (k < EMB) {
        v = W1[(size_t)k * CD + col];
    } else {
        int s = k - EMB;
        if (s < NSCEN) {
            for (int d = 0; d < 16; ++d)
                v += table[s * 16 + d] * W1[(size_t)(EMB + s * 16 + d) * CD + col];
        }
    }
    W1T[e] = f2bf(v);
}

__global__ __launch_bounds__(512, 4)
void scorer_mfma(const float* __restrict__ emb,
                 const int* __restrict__ ids,
                 const float* __restrict__ mask,
                 const ushort* __restrict__ W1T,
                 const float* __restrict__ b1,
                 const float* __restrict__ W2,
                 const float* __restrict__ b2,
                 float* __restrict__ out) {
    __shared__ __align__(16) ushort Bq[2][QB];     // 2 x 28 KB B quarter-buffers
    __shared__ __align__(16) ushort bagb[8][32][32]; // per-wave bag rows (wave-local!)

    const int t    = threadIdx.x;
    const int w    = t >> 6;       // wave 0..7, owns rows w*32..w*32+31
    const int lane = t & 63;
    const int lr   = lane & 15;
    const int lg   = lane >> 4;
    const int row0 = blockIdx.x * 256;

    // ================== startup vmem burst (all issued before any VALU phase) ====
    // bag inputs: lane l -> row w*32+(l&31), half (l>>5): slots half*16..+16
    const int hrow = row0 + w * 32 + (lane & 31);
    const int*   idrow = ids  + (size_t)hrow * 32 + (lane >> 5) * 16;
    const float* mrow  = mask + (size_t)hrow * 32 + (lane >> 5) * 16;
    int4   iv0 = ((const int4*)idrow)[0],  iv1 = ((const int4*)idrow)[1],
           iv2 = ((const int4*)idrow)[2],  iv3 = ((const int4*)idrow)[3];
    float4 mv0 = ((const float4*)mrow)[0], mv1 = ((const float4*)mrow)[1],
           mv2 = ((const float4*)mrow)[2], mv3 = ((const float4*)mrow)[3];

    const float* ap = emb + (size_t)(row0 + w * 32 + lr) * EMB + (lg << 3);
    fv4 aA[2][2], aB[2][2];
#define LOADA(dst, kks) do {                                   \
    const float* _p = ap + (kks) * 32;                         \
    dst[0][0] = *(const fv4*)(_p);                             \
    dst[0][1] = *(const fv4*)(_p + 4);                         \
    dst[1][0] = *(const fv4*)(_p + 16 * EMB);                  \
    dst[1][1] = *(const fv4*)(_p + 16 * EMB + 4);              \
} while (0)
    LOADA(aA, 0);   // first A k-step in flight during histogram

    uint4 f0, f1, f2, f3;
#define ISSUE_FILL(qs) do {                                                  \
    const uint* _g = (const uint*)((const char*)W1T + (size_t)(qs) * 4096);  \
    f0 = *(const uint4*)(_g + (t)        * 4);                               \
    f1 = *(const uint4*)(_g + (t + 512)  * 4);                               \
    f2 = *(const uint4*)(_g + (t + 1024) * 4);                               \
    if (t < 256) f3 = *(const uint4*)(_g + (t + 1536) * 4);                  \
} while (0)
#define WRITE_FILL(bufi) do {                                                \
    uint* _l = (uint*)&Bq[bufi][0];                                          \
    *(uint4*)(_l + (t)        * 4) = f0;                                     \
    *(uint4*)(_l + (t + 512)  * 4) = f1;                                     \
    *(uint4*)(_l + (t + 1024) * 4) = f2;                                     \
    if (t < 256) *(uint4*)(_l + (t + 1536) * 4) = f3;                        \
} while (0)
    ISSUE_FILL(0);   // quarter 0 in flight during histogram

    // ================== histogram: pure VALU, in-register, no atomics ============
    float bin[NSCEN];
#pragma unroll
    for (int s = 0; s < NSCEN; ++s) bin[s] = 0.f;
    float cnt = 0.f;
#define HSLOT(idv, mvv) do {                                   \
    cnt += mvv;                                                \
    _Pragma("unroll")                                          \
    for (int s = 0; s < NSCEN; ++s)                            \
        bin[s] += (idv == s) ? mvv : 0.f;                      \
} while (0)
    HSLOT(iv0.x, mv0.x); HSLOT(iv0.y, mv0.y); HSLOT(iv0.z, mv0.z); HSLOT(iv0.w, mv0.w);
    HSLOT(iv1.x, mv1.x); HSLOT(iv1.y, mv1.y); HSLOT(iv1.z, mv1.z); HSLOT(iv1.w, mv1.w);
    HSLOT(iv2.x, mv2.x); HSLOT(iv2.y, mv2.y); HSLOT(iv2.z, mv2.z); HSLOT(iv2.w, mv2.w);
    HSLOT(iv3.x, mv3.x); HSLOT(iv3.y, mv3.y); HSLOT(iv3.z, mv3.z); HSLOT(iv3.w, mv3.w);
#undef HSLOT
    // merge the two half-row lanes (l <-> l^32)
    cnt += __shfl_xor(cnt, 32);
#pragma unroll
    for (int s = 0; s < NSCEN; ++s) bin[s] += __shfl_xor(bin[s], 32);
    {
        float rc = 1.0f / fmaxf(cnt, 1.0f);
        if (lane < 32) {   // lane l writes row w*32+l (wave-local: no barrier needed)
            uint u[16];
#pragma unroll
            for (int p = 0; p < 9; ++p) u[p] = cvt2(bin[2 * p] * rc, bin[2 * p + 1] * rc);
            u[9] = cvt2(bin[18] * rc, 0.f);
#pragma unroll
            for (int p = 10; p < 16; ++p) u[p] = 0u;
            ushort* bp = &bagb[w][lane][0];
#pragma unroll
            for (int q = 0; q < 4; ++q)
                *(uint4*)(bp + q * 8) = make_uint4(u[4 * q], u[4 * q + 1], u[4 * q + 2], u[4 * q + 3]);
        }
    }

    WRITE_FILL(0);     // Bq0 <- quarter 0
    ISSUE_FILL(6);     // quarter 1
    __syncthreads();   // Bq0 ready

    // ================== MFMA stream: A = only steady-state vmem traffic ==========
    f32x4 acc[2][4];
#pragma unroll
    for (int i = 0; i < 2; ++i)
#pragma unroll
        for (int j = 0; j < 4; ++j) acc[i][j] = (f32x4)0.f;

    short8 bqr[4];
#define LDSB(bufi, ksl) do {                                   \
    const ushort* _l = &Bq[bufi][(ksl) * 2048 + lane * 8];     \
    bqr[0] = *(const short8*)(_l);                             \
    bqr[1] = *(const short8*)(_l + 512);                       \
    bqr[2] = *(const short8*)(_l + 1024);                      \
    bqr[3] = *(const short8*)(_l + 1536);                      \
} while (0)

#define STEP(areg) do {                                                     \
    short8 _fa[2];                                                          \
    _Pragma("unroll")                                                       \
    for (int _rt = 0; _rt < 2; ++_rt) {                                     \
        union { uint u[4]; short8 s; } _c;                                  \
        _c.u[0] = cvt2(areg[_rt][0][0], areg[_rt][0][1]);                   \
        _c.u[1] = cvt2(areg[_rt][0][2], areg[_rt][0][3]);                   \
        _c.u[2] = cvt2(areg[_rt][1][0], areg[_rt][1][1]);                   \
        _c.u[3] = cvt2(areg[_rt][1][2], areg[_rt][1][3]);                   \
        _fa[_rt] = _c.s;                                                    \
    }                                                                       \
    _Pragma("unroll")                                                       \
    for (int _rt = 0; _rt < 2; ++_rt) {                                     \
        acc[_rt][0] = __builtin_amdgcn_mfma_f32_16x16x32_bf16(_fa[_rt], bqr[0], acc[_rt][0], 0, 0, 0); \
        acc[_rt][1] = __builtin_amdgcn_mfma_f32_16x16x32_bf16(_fa[_rt], bqr[1], acc[_rt][1], 0, 0, 0); \
        acc[_rt][2] = __builtin_amdgcn_mfma_f32_16x16x32_bf16(_fa[_rt], bqr[2], acc[_rt][2], 0, 0, 0); \
        acc[_rt][3] = __builtin_amdgcn_mfma_f32_16x16x32_bf16(_fa[_rt], bqr[3], acc[_rt][3], 0, 0, 0); \
    }                                                                       \
} while (0)

#define QUARTER(bufi, qs) do {                                              \
    _Pragma("unroll")                                                       \
    for (int _ksl = 0; _ksl < 6; ++_ksl) {                                  \
        const int _ks = (qs) + _ksl;                                        \
        LDSB(bufi, _ksl);                                                   \
        if ((_ks & 1) == 0) {                                               \
            if (_ks + 1 <= 23) LOADA(aB, _ks + 1);                          \
            STEP(aA);                                                       \
        } else {                                                            \
            if (_ks + 1 <= 23) LOADA(aA, _ks + 1);                          \
            STEP(aB);                                                       \
        }                                                                   \
    }                                                                       \
} while (0)

    // Q0: compute from Bq0; fill Bq1 (q1 regs in flight), issue q2
    WRITE_FILL(1);
    ISSUE_FILL(12);
    QUARTER(0, 0);
    __syncthreads();   // Bq1 ready; Bq0 free

    // Q1: compute from Bq1; fill Bq0 with q2, issue q3
    WRITE_FILL(0);
    ISSUE_FILL(18);
    QUARTER(1, 6);
    __syncthreads();   // Bq0 ready; Bq1 free

    // Q2: compute from Bq0; fill Bq1 with q3 (k-steps 18-24 incl. bag chunk)
    WRITE_FILL(1);
    QUARTER(0, 12);
    __syncthreads();   // Bq1 ready

    // Q3: compute from Bq1 (6 emb steps + bag step at local chunk 6)
    QUARTER(1, 18);
    {
        short8 ab[2];
        ab[0] = *(const short8*)&bagb[w][lr][lg << 3];
        ab[1] = *(const short8*)&bagb[w][16 + lr][lg << 3];
        LDSB(1, 6);
#pragma unroll
        for (int rt = 0; rt < 2; ++rt) {
            acc[rt][0] = __builtin_amdgcn_mfma_f32_16x16x32_bf16(ab[rt], bqr[0], acc[rt][0], 0, 0, 0);
            acc[rt][1] = __builtin_amdgcn_mfma_f32_16x16x32_bf16(ab[rt], bqr[1], acc[rt][1], 0, 0, 0);
            acc[rt][2] = __builtin_amdgcn_mfma_f32_16x16x32_bf16(ab[rt], bqr[2], acc[rt][2], 0, 0, 0);
            acc[rt][3] = __builtin_amdgcn_mfma_f32_16x16x32_bf16(ab[rt], bqr[3], acc[rt][3], 0, 0, 0);
        }
    }

    // ================== epilogue: bias + relu + dot(W2) + tanh ===================
    float b1v[4], w2v[4];
#pragma unroll
    for (int ct = 0; ct < 4; ++ct) {
        int c = ct * 16 + lr;
        b1v[ct] = b1[c];
        w2v[ct] = W2[c];
    }
    const float b2v = b2[0];
#pragma unroll
    for (int rt = 0; rt < 2; ++rt) {
#pragma unroll
        for (int r = 0; r < 4; ++r) {
            float p = 0.f;
#pragma unroll
            for (int ct = 0; ct < 4; ++ct) {
                float h = acc[rt][ct][r] + b1v[ct];
                p += fmaxf(h, 0.f) * w2v[ct];
            }
            p += __shfl_xor(p, 1);
            p += __shfl_xor(p, 2);
            p += __shfl_xor(p, 4);
            p += __shfl_xor(p, 8);
            if (lr == 0)
                out[row0 + w * 32 + rt * 16 + (lg << 2) + r] = tanhf(p + b2v);
        }
    }
#undef ISSUE_FILL
#undef WRITE_FILL
#undef LOADA
#undef LDSB
#undef STEP
#undef QUARTER
}

extern "C" void kernel_launch(void* const* d_in, const int* in_sizes, int n_in,
                              void* d_out, int out_size, void* d_ws, size_t ws_size,
                              hipStream_t stream) {
    const float* emb   = (const float*)d_in[0];
    const int*   ids   = (const int*)d_in[1];
    const float* mask  = (const float*)d_in[2];
    const float* table = (const float*)d_in[3];
    const float* W1    = (const float*)d_in[4];
    const float* b1    = (const float*)d_in[5];
    const float* W2    = (const float*)d_in[6];
    const float* b2    = (const float*)d_in[7];
    float* out  = (float*)d_out;
    ushort* W1T = (ushort*)d_ws;   // 51200 bf16 = 100 KB

    prep_W1T<<<200, 256, 0, stream>>>(table, W1, W1T);
    const int nblocks = out_size / 256;   // 512
    scorer_mfma<<<nblocks, 512, 0, stream>>>(emb, ids, mask, W1T, b1, W2, b2, out);
}

// Round 12
// 89.673 us; speedup vs baseline: 2.9379x; 1.0202x over previous
//
#include <hip/hip_runtime.h>
#include <hip/hip_bf16.h>
#include <math.h>

using short8 = __attribute__((ext_vector_type(8))) short;
using f32x4  = __attribute__((ext_vector_type(4))) float;
using fv4    = __attribute__((ext_vector_type(4))) float;

#define EMB 768
#define CD  64
#define NSCEN 19
#define KSTEPS 24            // 768 / 32
#define NCHUNKS (25 * 4)     // (24 emb + 1 bag) k-steps x 4 col-tiles, 512 bf16 each
#define QB 14336             // ushorts per LDS B quarter-buffer (28 KB)
#define BM 128               // rows per block (2 rounds of blocks per CU -> tail overlap)

__device__ __forceinline__ ushort f2bf(float x) {
    unsigned u = __float_as_uint(x);
    u += 0x7FFFu + ((u >> 16) & 1u);   // RNE
    return (ushort)(u >> 16);
}

// packed f32x2 -> bf16x2 (v_cvt_pk_bf16_f32)
__device__ __forceinline__ uint cvt2(float x, float y) {
    __hip_bfloat162 h = __float22bfloat162_rn(make_float2(x, y));
    union { __hip_bfloat162 h; uint u; } c;
    c.h = h;
    return c.u;
}

// Pre-fragment B = [W1(768x64) ; P(32x64)] into bf16 wave-chunks of 512 elems:
// chunk c = ks*4+ct; element r = lane*8+j  <->  B[k = ks*32+(lane>>4)*8+j][col = ct*16+(lane&15)]
__global__ void prep_W1T(const float* __restrict__ table,
                         const float* __restrict__ W1,
                         ushort* __restrict__ W1T) {
    int e = blockIdx.x * 256 + threadIdx.x;      // 0 .. 51200
    if (e >= NCHUNKS * 512) return;
    int chunk = e >> 9, r = e & 511;
    int lane = r >> 3, j = r & 7;
    int ks = chunk >> 2, ct = chunk & 3;
    int col = ct * 16 + (lane & 15);
    int k = ks * 32 + ((lane >> 4) << 3) + j;
    float v = 0.f;
    if (k < EMB) {
        v = W1[(size_t)k * CD + col];
    } else {
        int s = k - EMB;
        if (s < NSCEN) {
            for (int d = 0; d < 16; ++d)
                v += table[s * 16 + d] * W1[(size_t)(EMB + s * 16 + d) * CD + col];
        }
    }
    W1T[e] = f2bf(v);
}

__global__ __launch_bounds__(512, 4)
void scorer_mfma(const float* __restrict__ emb,
                 const int* __restrict__ ids,
                 const float* __restrict__ mask,
                 const ushort* __restrict__ W1T,
                 const float* __restrict__ b1,
                 const float* __restrict__ W2,
                 const float* __restrict__ b2,
                 float* __restrict__ out) {
    __shared__ __align__(16) ushort Bq[2][QB];       // 2 x 28 KB B quarter-buffers
    __shared__ __align__(16) ushort bagb[8][16][32]; // per-wave bag rows (wave-local)

    const int t    = threadIdx.x;
    const int w    = t >> 6;       // wave 0..7, owns rows w*16..w*16+15
    const int lane = t & 63;
    const int lr   = lane & 15;
    const int lg   = lane >> 4;
    const int row0 = blockIdx.x * BM;

    // ================== startup vmem burst (before any VALU phase) ===============
    // bag inputs: 4 lanes per row; lane l -> row w*16+(l&15), slot-quarter q=(l>>4)
    const int hrow = row0 + w * 16 + lr;
    const int*   idrow = ids  + (size_t)hrow * 32 + lg * 8;
    const float* mrow  = mask + (size_t)hrow * 32 + lg * 8;
    int4   iv0 = ((const int4*)idrow)[0],  iv1 = ((const int4*)idrow)[1];
    float4 mv0 = ((const float4*)mrow)[0], mv1 = ((const float4*)mrow)[1];

    const float* ap = emb + (size_t)(row0 + w * 16 + lr) * EMB + (lg << 3);
    fv4 aA[2], aB[2];
#define LOADA(dst, kks) do {                                   \
    const float* _p = ap + (kks) * 32;                         \
    dst[0] = *(const fv4*)(_p);                                \
    dst[1] = *(const fv4*)(_p + 4);                            \
} while (0)
    LOADA(aA, 0);   // first A k-step in flight during histogram

    uint4 f0, f1, f2, f3;
#define ISSUE_FILL(qs) do {                                                  \
    const uint* _g = (const uint*)((const char*)W1T + (size_t)(qs) * 4096);  \
    f0 = *(const uint4*)(_g + (t)        * 4);                               \
    f1 = *(const uint4*)(_g + (t + 512)  * 4);                               \
    f2 = *(const uint4*)(_g + (t + 1024) * 4);                               \
    if (t < 256) f3 = *(const uint4*)(_g + (t + 1536) * 4);                  \
} while (0)
#define WRITE_FILL(bufi) do {                                                \
    uint* _l = (uint*)&Bq[bufi][0];                                          \
    *(uint4*)(_l + (t)        * 4) = f0;                                     \
    *(uint4*)(_l + (t + 512)  * 4) = f1;                                     \
    *(uint4*)(_l + (t + 1024) * 4) = f2;                                     \
    if (t < 256) *(uint4*)(_l + (t + 1536) * 4) = f3;                        \
} while (0)
    ISSUE_FILL(0);   // quarter 0 in flight during histogram

    // ================== histogram: pure VALU, in-register, no atomics ============
    float bin[NSCEN];
#pragma unroll
    for (int s = 0; s < NSCEN; ++s) bin[s] = 0.f;
    float cnt = 0.f;
#define HSLOT(idv, mvv) do {                                   \
    cnt += mvv;                                                \
    _Pragma("unroll")                                          \
    for (int s = 0; s < NSCEN; ++s)                            \
        bin[s] += (idv == s) ? mvv : 0.f;                      \
} while (0)
    HSLOT(iv0.x, mv0.x); HSLOT(iv0.y, mv0.y); HSLOT(iv0.z, mv0.z); HSLOT(iv0.w, mv0.w);
    HSLOT(iv1.x, mv1.x); HSLOT(iv1.y, mv1.y); HSLOT(iv1.z, mv1.z); HSLOT(iv1.w, mv1.w);
#undef HSLOT
    // merge the four slot-quarter lanes (l ^16, ^32)
    cnt += __shfl_xor(cnt, 16);
    cnt += __shfl_xor(cnt, 32);
#pragma unroll
    for (int s = 0; s < NSCEN; ++s) {
        bin[s] += __shfl_xor(bin[s], 16);
        bin[s] += __shfl_xor(bin[s], 32);
    }
    {
        float rc = 1.0f / fmaxf(cnt, 1.0f);
        if (lane < 16) {   // lane l writes row w*16+l (wave-local: no barrier needed)
            uint u[16];
#pragma unroll
            for (int p = 0; p < 9; ++p) u[p] = cvt2(bin[2 * p] * rc, bin[2 * p + 1] * rc);
            u[9] = cvt2(bin[18] * rc, 0.f);
#pragma unroll
            for (int p = 10; p < 16; ++p) u[p] = 0u;
            ushort* bp = &bagb[w][lane][0];
#pragma unroll
            for (int q = 0; q < 4; ++q)
                *(uint4*)(bp + q * 8) = make_uint4(u[4 * q], u[4 * q + 1], u[4 * q + 2], u[4 * q + 3]);
        }
    }

    WRITE_FILL(0);     // Bq0 <- quarter 0
    ISSUE_FILL(6);     // quarter 1
    __syncthreads();   // Bq0 ready

    // ================== MFMA stream: A = only steady-state vmem traffic ==========
    f32x4 acc[4];
#pragma unroll
    for (int j = 0; j < 4; ++j) acc[j] = (f32x4)0.f;

    short8 bqr[4];
#define LDSB(bufi, ksl) do {                                   \
    const ushort* _l = &Bq[bufi][(ksl) * 2048 + lane * 8];     \
    bqr[0] = *(const short8*)(_l);                             \
    bqr[1] = *(const short8*)(_l + 512);                       \
    bqr[2] = *(const short8*)(_l + 1024);                      \
    bqr[3] = *(const short8*)(_l + 1536);                      \
} while (0)

#define STEP(areg) do {                                                     \
    union { uint u[4]; short8 s; } _c;                                      \
    _c.u[0] = cvt2(areg[0][0], areg[0][1]);                                 \
    _c.u[1] = cvt2(areg[0][2], areg[0][3]);                                 \
    _c.u[2] = cvt2(areg[1][0], areg[1][1]);                                 \
    _c.u[3] = cvt2(areg[1][2], areg[1][3]);                                 \
    acc[0] = __builtin_amdgcn_mfma_f32_16x16x32_bf16(_c.s, bqr[0], acc[0], 0, 0, 0); \
    acc[1] = __builtin_amdgcn_mfma_f32_16x16x32_bf16(_c.s, bqr[1], acc[1], 0, 0, 0); \
    acc[2] = __builtin_amdgcn_mfma_f32_16x16x32_bf16(_c.s, bqr[2], acc[2], 0, 0, 0); \
    acc[3] = __builtin_amdgcn_mfma_f32_16x16x32_bf16(_c.s, bqr[3], acc[3], 0, 0, 0); \
} while (0)

#define QUARTER(bufi, qs) do {                                              \
    _Pragma("unroll")                                                       \
    for (int _ksl = 0; _ksl < 6; ++_ksl) {                                  \
        const int _ks = (qs) + _ksl;                                        \
        LDSB(bufi, _ksl);                                                   \
        if ((_ks & 1) == 0) {                                               \
            if (_ks + 1 <= 23) LOADA(aB, _ks + 1);                          \
            STEP(aA);                                                       \
        } else {                                                            \
            if (_ks + 1 <= 23) LOADA(aA, _ks + 1);                          \
            STEP(aB);                                                       \
        }                                                                   \
    }                                                                       \
} while (0)

    // Q0: compute from Bq0; fill Bq1 (q1 regs in flight), issue q2
    WRITE_FILL(1);
    ISSUE_FILL(12);
    QUARTER(0, 0);
    __syncthreads();   // Bq1 ready; Bq0 free

    // Q1: compute from Bq1; fill Bq0 with q2, issue q3
    WRITE_FILL(0);
    ISSUE_FILL(18);
    QUARTER(1, 6);
    __syncthreads();   // Bq0 ready; Bq1 free

    // Q2: compute from Bq0; fill Bq1 with q3 (k-steps 18-24 incl. bag chunk)
    WRITE_FILL(1);
    QUARTER(0, 12);
    __syncthreads();   // Bq1 ready

    // Q3: compute from Bq1 (6 emb steps + bag step at local chunk 6)
    QUARTER(1, 18);
    {
        short8 ab = *(const short8*)&bagb[w][lr][lg << 3];
        LDSB(1, 6);
        acc[0] = __builtin_amdgcn_mfma_f32_16x16x32_bf16(ab, bqr[0], acc[0], 0, 0, 0);
        acc[1] = __builtin_amdgcn_mfma_f32_16x16x32_bf16(ab, bqr[1], acc[1], 0, 0, 0);
        acc[2] = __builtin_amdgcn_mfma_f32_16x16x32_bf16(ab, bqr[2], acc[2], 0, 0, 0);
        acc[3] = __builtin_amdgcn_mfma_f32_16x16x32_bf16(ab, bqr[3], acc[3], 0, 0, 0);
    }

    // ================== epilogue: bias + relu + dot(W2) + tanh ===================
    float b1v[4], w2v[4];
#pragma unroll
    for (int ct = 0; ct < 4; ++ct) {
        int c = ct * 16 + lr;
        b1v[ct] = b1[c];
        w2v[ct] = W2[c];
    }
    const float b2v = b2[0];
#pragma unroll
    for (int r = 0; r < 4; ++r) {
        float p = 0.f;
#pragma unroll
        for (int ct = 0; ct < 4; ++ct) {
            float h = acc[ct][r] + b1v[ct];
            p += fmaxf(h, 0.f) * w2v[ct];
        }
        p += __shfl_xor(p, 1);
        p += __shfl_xor(p, 2);
        p += __shfl_xor(p, 4);
        p += __shfl_xor(p, 8);
        if (lr == 0)
            out[row0 + w * 16 + (lg << 2) + r] = tanhf(p + b2v);
    }
#undef ISSUE_FILL
#undef WRITE_FILL
#undef LOADA
#undef LDSB
#undef STEP
#undef QUARTER
}

extern "C" void kernel_launch(void* const* d_in, const int* in_sizes, int n_in,
                              void* d_out, int out_size, void* d_ws, size_t ws_size,
                              hipStream_t stream) {
    const float* emb   = (const float*)d_in[0];
    const int*   ids   = (const int*)d_in[1];
    const float* mask  = (const float*)d_in[2];
    const float* table = (const float*)d_in[3];
    const float* W1    = (const float*)d_in[4];
    const float* b1    = (const float*)d_in[5];
    const float* W2    = (const float*)d_in[6];
    const float* b2    = (const float*)d_in[7];
    float* out  = (float*)d_out;
    ushort* W1T = (ushort*)d_ws;   // 51200 bf16 = 100 KB

    prep_W1T<<<200, 256, 0, stream>>>(table, W1, W1T);
    const int nblocks = out_size / BM;   // 1024
    scorer_mfma<<<nblocks, 512, 0, stream>>>(emb, ids, mask, W1T, b1, W2, b2, out);
}